// Round 10
// baseline (1016.101 us; speedup 1.0000x reference)
//
#include <hip/hip_runtime.h>
#include <hip/hip_cooperative_groups.h>
#include <hip/hip_bf16.h>
#include <math.h>

namespace cg = cooperative_groups;

typedef __bf16 bf16;
typedef __bf16 v8bf __attribute__((ext_vector_type(8)));
typedef __bf16 v4bf __attribute__((ext_vector_type(4)));
typedef float  v4f  __attribute__((ext_vector_type(4)));

#define FDIM 256
#define BKT_CAP 8192
#define AROW 264        // LDS A row stride (528B -> 2-way bank aliasing, free)
#define P3CAP 4096      // >= ceil(E/256) = 3907
#define SMEM_A 68640    // union: p4 (68624) > p3 (35856) > gemm (33792) > k1 (6144)

// ---------------- utility ----------------

__global__ __launch_bounds__(256) void flag_kernel(float* __restrict__ out, int n) {
  int i = blockIdx.x * 256 + threadIdx.x;
  if (i < n) out[i] = 1.0e9f;
}

// =================== device-side phase bodies (shared by mega + fallback) =========

// ---- k1: vb<256 Wt1 transpose; 256..511 per-chunk hist; vb==512 V/cc ----
__device__ void k1_body(int vb, char* sm, const float* __restrict__ W1,
                        const float* __restrict__ W2, bf16* __restrict__ Wt1,
                        const int* __restrict__ dst, int* __restrict__ phist,
                        const float* __restrict__ Wl, const float* __restrict__ b2,
                        const float* __restrict__ bl, float4* __restrict__ V,
                        float* __restrict__ cc, int E, int N) {
  int* h = (int*)sm;                       // 1KB
  float* sWl = (float*)(sm + 1024);        // 4KB
  float* red = (float*)(sm + 5120);        // 1KB
  int t = threadIdx.x;
  if (vb < 256) {
    Wt1[t * FDIM + vb] = (bf16)W1[vb * FDIM + t];
  } else if (vb < 512) {
    int pb = vb - 256;  // contiguous chunk pb, same chunking as p3
    int chunk = (E + 255) >> 8;
    int lo = pb * chunk;
    int hi = lo + chunk; if (hi > E) hi = E;
    h[t] = 0;
    __syncthreads();
    for (int e = lo + t; e < hi; e += 256) {
      int d = dst[e];
      d = d < 0 ? 0 : (d >= N ? N - 1 : d);
      atomicAdd(&h[d >> 8], 1);
    }
    __syncthreads();
    phist[pb * 256 + t] = h[t];
    __syncthreads();
  } else {
#pragma unroll
    for (int j = 0; j < 4; ++j) sWl[j * 256 + t] = Wl[j * 256 + t];
    __syncthreads();
    const float* w2row = W2 + (size_t)t * FDIM;
    float4 acc = make_float4(0.f, 0.f, 0.f, 0.f);
    for (int j = 0; j < 256; ++j) {
      float w = w2row[j];
      acc.x += w * sWl[2 * j + 0];
      acc.y += w * sWl[2 * j + 1];
      acc.z += w * sWl[512 + 2 * j + 0];
      acc.w += w * sWl[512 + 2 * j + 1];
    }
    V[t] = acc;
    float bj = b2[t];
    red[t] = bj * (sWl[2 * t + 0] + sWl[512 + 2 * t + 0]);
    __syncthreads();
    if (t == 0) {
      float s = 0.f;
      for (int j = 0; j < 256; ++j) s += red[j];
      cc[0] = s + bl[0];
    }
    __syncthreads();
    red[t] = bj * (sWl[2 * t + 1] + sWl[512 + 2 * t + 1]);
    __syncthreads();
    if (t == 0) {
      float s = 0.f;
      for (int j = 0; j < 256; ++j) s += red[j];
      cc[1] = s + bl[1];
    }
    __syncthreads();
  }
}

// ---- p2: bucket scan -> bbase/offs[N]; per-chunk run bases -> pbase (1 block) ----
__device__ void p2_body(char* sm, const int* __restrict__ phist,
                        int* __restrict__ bbase, int* __restrict__ pbase,
                        int* __restrict__ offs, int nbkt, int Nn) {
  int* wsum = (int*)sm;
  int t = threadIdx.x, lane = t & 63, wv = t >> 6;
  int v = 0;
  for (int pb = 0; pb < 256; ++pb) v += phist[pb * 256 + t];  // coalesced across t
  if (t >= nbkt) v = 0;
  int x = v;
#pragma unroll
  for (int d = 1; d < 64; d <<= 1) {
    int y = __shfl_up(x, d, 64);
    if (lane >= d) x += y;
  }
  if (lane == 63) wsum[wv] = x;
  __syncthreads();
  int woff = 0;
  if (wv >= 1) woff += wsum[0];
  if (wv >= 2) woff += wsum[1];
  if (wv >= 3) woff += wsum[2];
  int incl = woff + x;
  int excl = incl - v;
  if (t < nbkt) bbase[t] = excl;
  if (t == 255) {
    bbase[nbkt] = incl;
    offs[Nn] = incl;
  }
  int run = excl;
#pragma unroll 4
  for (int pb = 0; pb < 256; ++pb) {
    pbase[pb * 256 + t] = run;
    run += phist[pb * 256 + t];
  }
}

// ---- gemm: bufT = bf16(x @ W1), grid-strided tiles ----
__device__ void stage64(const float* __restrict__ A, bf16* __restrict__ As,
                        int row0, int M, int tid) {
#pragma unroll
  for (int j = 0; j < 8; ++j) {
    int g = j * 2048 + tid * 8;
    int r = g >> 8, c = g & 255;
    int gr = row0 + r; if (gr >= M) gr = M - 1;
    const float* p = A + (size_t)gr * FDIM + c;
    float4 f0 = *reinterpret_cast<const float4*>(p);
    float4 f1 = *reinterpret_cast<const float4*>(p + 4);
    v8bf o;
    o[0] = (bf16)f0.x; o[1] = (bf16)f0.y; o[2] = (bf16)f0.z; o[3] = (bf16)f0.w;
    o[4] = (bf16)f1.x; o[5] = (bf16)f1.y; o[6] = (bf16)f1.z; o[7] = (bf16)f1.w;
    *reinterpret_cast<v8bf*>(As + r * AROW + c) = o;
  }
}

__device__ void gemm_body(const float* __restrict__ A, const bf16* __restrict__ Bt,
                          bf16* __restrict__ C, int M, int bid, int nblocks,
                          bf16* As) {
  const int K = FDIM, N = FDIM;
  int tid = threadIdx.x;
  int wave = tid >> 6;
  int lane = tid & 63;
  int l15 = lane & 15, quad = lane >> 4;

  v8bf bfr[4][8];
#pragma unroll
  for (int nn = 0; nn < 4; ++nn) {
    const bf16* bp = Bt + (size_t)(wave * 64 + nn * 16 + l15) * K + quad * 8;
#pragma unroll
    for (int kk = 0; kk < 8; ++kk)
      bfr[nn][kk] = *reinterpret_cast<const v8bf*>(bp + kk * 32);
  }

  int ntiles = (M + 63) >> 6;
  for (int tile = bid; tile < ntiles; tile += nblocks) {
    int row0 = tile * 64;
    __syncthreads();
    stage64(A, As, row0, M, tid);
    __syncthreads();

#pragma unroll
    for (int st = 0; st < 4; ++st) {
      v8bf afr[8];
#pragma unroll
      for (int kk = 0; kk < 8; ++kk)
        afr[kk] = *reinterpret_cast<const v8bf*>(As + (st * 16 + l15) * AROW + quad * 8 + kk * 32);

      v4f acc[4];
#pragma unroll
      for (int nn = 0; nn < 4; ++nn) acc[nn] = (v4f){0.f, 0.f, 0.f, 0.f};

#pragma unroll
      for (int kk = 0; kk < 8; ++kk)
#pragma unroll
        for (int nn = 0; nn < 4; ++nn)
          acc[nn] = __builtin_amdgcn_mfma_f32_16x16x32_bf16(afr[kk], bfr[nn][kk], acc[nn], 0, 0, 0);

#pragma unroll
      for (int nn = 0; nn < 4; ++nn)
#pragma unroll
        for (int r = 0; r < 4; ++r) {
          int row = row0 + st * 16 + quad * 4 + r;
          int col = wave * 64 + nn * 16 + l15;
          if (row < M) C[(size_t)row * N + col] = (bf16)acc[nn][r];
        }
    }
  }
}

// ---- p3: LDS-staged scatter, coalesced copy-out (round-8 proven) ----
__device__ void p3_body(int pb, char* sm, const int* __restrict__ src,
                        const int* __restrict__ dst, const float* __restrict__ ew,
                        const int* __restrict__ phist, const int* __restrict__ pbase,
                        uint2* __restrict__ tmp, int E, int N) {
  uint2* ent = (uint2*)sm;                 // 32KB
  int* lbase = (int*)(sm + 32768);
  int* lcnt  = (int*)(sm + 33792);
  int* gbase = (int*)(sm + 34816);
  int* wsum  = (int*)(sm + 35840);
  int t = threadIdx.x, lane = t & 63, wv = t >> 6;
  int chunk = (E + 255) >> 8;
  int lo = pb * chunk;
  int hi = lo + chunk; if (hi > E) hi = E;

  int v = phist[pb * 256 + t];
  int x = v;
#pragma unroll
  for (int d = 1; d < 64; d <<= 1) {
    int y = __shfl_up(x, d, 64);
    if (lane >= d) x += y;
  }
  if (lane == 63) wsum[wv] = x;
  gbase[t] = pbase[pb * 256 + t];
  lcnt[t] = 0;
  __syncthreads();
  int woff = 0;
  if (wv >= 1) woff += wsum[0];
  if (wv >= 2) woff += wsum[1];
  if (wv >= 3) woff += wsum[2];
  lbase[t] = woff + x - v;
  __syncthreads();

  for (int e = lo + t; e < hi; e += 256) {
    int d = dst[e];
    d = d < 0 ? 0 : (d >= N ? N - 1 : d);
    int b = d >> 8;
    int sv = src[e];
    sv = sv < 0 ? 0 : (sv >= N ? N - 1 : sv);
    unsigned int u = __float_as_uint(ew[e]);
    unsigned int wbits = ((u + 0x7FFFu + ((u >> 16) & 1u)) & 0xFFFF0000u);  // RN bf16
    unsigned int meta = wbits | (unsigned int)(sv & 0xFFFF);
    int r = atomicAdd(&lcnt[b], 1);
    int pos = lbase[b] + r;
    if (pos >= 0 && pos < P3CAP) ent[pos] = make_uint2(meta, (unsigned int)d);
  }
  __syncthreads();

  int count = hi - lo;
  for (int i = t; i < count; i += 256) {
    uint2 en = ent[i];
    int b = (int)(en.y >> 8);               // bucket (d clamped < N)
    int dest = gbase[b] + (i - lbase[b]);   // contiguous within each run
    if (dest >= 0 && dest < E) tmp[dest] = en;
  }
  __syncthreads();
}

// ---- p4: per-bucket LDS count-sort -> pmeta + node offsets ----
__device__ void p4_body(int b, char* sm, const uint2* __restrict__ tmp,
                        const int* __restrict__ bbase, unsigned int* __restrict__ pmeta,
                        int* __restrict__ offs, int Nn, int E) {
  uint2* ent = (uint2*)sm;                 // 64KB
  int* h2  = (int*)(sm + 65536);
  int* ex2 = (int*)(sm + 66560);
  int* c2  = (int*)(sm + 67584);
  int* wsum = (int*)(sm + 68608);
  int t = threadIdx.x, lane = t & 63, wv = t >> 6;
  int s0 = bbase[b], s1 = bbase[b + 1];
  int count = s1 - s0;
  if (count < 0) count = 0;
  if (count > BKT_CAP) count = BKT_CAP;
  for (int i = t; i < count; i += 256) ent[i] = tmp[s0 + i];
  h2[t] = 0; c2[t] = 0;
  __syncthreads();
  for (int i = t; i < count; i += 256) atomicAdd(&h2[ent[i].y & 255u], 1);
  __syncthreads();
  int v = h2[t];
  int x = v;
#pragma unroll
  for (int d = 1; d < 64; d <<= 1) {
    int y = __shfl_up(x, d, 64);
    if (lane >= d) x += y;
  }
  if (lane == 63) wsum[wv] = x;
  __syncthreads();
  int woff = 0;
  if (wv >= 1) woff += wsum[0];
  if (wv >= 2) woff += wsum[1];
  if (wv >= 3) woff += wsum[2];
  int excl = woff + x - v;
  ex2[t] = excl;
  int node = (b << 8) + t;
  if (node < Nn) offs[node] = s0 + excl;
  __syncthreads();
  for (int i = t; i < count; i += 256) {
    int l = (int)(ent[i].y & 255u);
    int r = atomicAdd(&c2[l], 1);
    int pos = s0 + ex2[l] + r;
    if (pos >= 0 && pos < E) pmeta[pos] = ent[i].x;
  }
  __syncthreads();
}

// ---- agg1G (proven 2048-block geometry): grid-stride + scalarized meta ----
__device__ void agg_body(const bf16* __restrict__ T, const unsigned int* __restrict__ pmeta,
                         const int* __restrict__ offsets, const float* __restrict__ bias,
                         const float4* __restrict__ V, float4* __restrict__ G,
                         int N, int E) {
  int wid = blockIdx.x * 4 + (threadIdx.x >> 6);
  int nw = gridDim.x * 4;
  int lane = threadIdx.x & 63;
  int f = lane * 4;
  const bf16* Tf = T + f;

  float4 bb = *reinterpret_cast<const float4*>(bias + f);
  float4 v0 = V[f + 0], v1 = V[f + 1], v2 = V[f + 2], v3 = V[f + 3];

  for (int node = wid; node < N; node += nw) {
    int nb = __builtin_amdgcn_readfirstlane(node);
    int beg = offsets[nb], end = offsets[nb + 1];
    beg = beg < 0 ? 0 : (beg > E ? E : beg);
    end = end < beg ? beg : (end > E ? E : end);
    int cnt = end - beg;
    const unsigned int* m = pmeta + beg;

    float a0 = 0.f, a1 = 0.f, a2 = 0.f, a3 = 0.f;
    int p = 0;
    for (; p + 8 <= cnt; p += 8) {
      unsigned int mv0 = m[p + 0], mv1 = m[p + 1], mv2 = m[p + 2], mv3 = m[p + 3];
      unsigned int mv4 = m[p + 4], mv5 = m[p + 5], mv6 = m[p + 6], mv7 = m[p + 7];
      v4bf t0 = *reinterpret_cast<const v4bf*>(Tf + ((size_t)(mv0 & 0xFFFFu) << 8));
      v4bf t1 = *reinterpret_cast<const v4bf*>(Tf + ((size_t)(mv1 & 0xFFFFu) << 8));
      v4bf t2 = *reinterpret_cast<const v4bf*>(Tf + ((size_t)(mv2 & 0xFFFFu) << 8));
      v4bf t3 = *reinterpret_cast<const v4bf*>(Tf + ((size_t)(mv3 & 0xFFFFu) << 8));
      v4bf t4 = *reinterpret_cast<const v4bf*>(Tf + ((size_t)(mv4 & 0xFFFFu) << 8));
      v4bf t5 = *reinterpret_cast<const v4bf*>(Tf + ((size_t)(mv5 & 0xFFFFu) << 8));
      v4bf t6 = *reinterpret_cast<const v4bf*>(Tf + ((size_t)(mv6 & 0xFFFFu) << 8));
      v4bf t7 = *reinterpret_cast<const v4bf*>(Tf + ((size_t)(mv7 & 0xFFFFu) << 8));
      float w0 = __uint_as_float(mv0 & 0xFFFF0000u);
      float w1 = __uint_as_float(mv1 & 0xFFFF0000u);
      float w2 = __uint_as_float(mv2 & 0xFFFF0000u);
      float w3 = __uint_as_float(mv3 & 0xFFFF0000u);
      float w4 = __uint_as_float(mv4 & 0xFFFF0000u);
      float w5 = __uint_as_float(mv5 & 0xFFFF0000u);
      float w6 = __uint_as_float(mv6 & 0xFFFF0000u);
      float w7 = __uint_as_float(mv7 & 0xFFFF0000u);
      a0 += w0 * (float)t0[0]; a1 += w0 * (float)t0[1]; a2 += w0 * (float)t0[2]; a3 += w0 * (float)t0[3];
      a0 += w1 * (float)t1[0]; a1 += w1 * (float)t1[1]; a2 += w1 * (float)t1[2]; a3 += w1 * (float)t1[3];
      a0 += w2 * (float)t2[0]; a1 += w2 * (float)t2[1]; a2 += w2 * (float)t2[2]; a3 += w2 * (float)t2[3];
      a0 += w3 * (float)t3[0]; a1 += w3 * (float)t3[1]; a2 += w3 * (float)t3[2]; a3 += w3 * (float)t3[3];
      a0 += w4 * (float)t4[0]; a1 += w4 * (float)t4[1]; a2 += w4 * (float)t4[2]; a3 += w4 * (float)t4[3];
      a0 += w5 * (float)t5[0]; a1 += w5 * (float)t5[1]; a2 += w5 * (float)t5[2]; a3 += w5 * (float)t5[3];
      a0 += w6 * (float)t6[0]; a1 += w6 * (float)t6[1]; a2 += w6 * (float)t6[2]; a3 += w6 * (float)t6[3];
      a0 += w7 * (float)t7[0]; a1 += w7 * (float)t7[1]; a2 += w7 * (float)t7[2]; a3 += w7 * (float)t7[3];
    }
    for (; p < cnt; ++p) {
      unsigned int mv = m[p];
      float w = __uint_as_float(mv & 0xFFFF0000u);
      v4bf tv = *reinterpret_cast<const v4bf*>(Tf + ((size_t)(mv & 0xFFFFu) << 8));
      a0 += w * (float)tv[0];
      a1 += w * (float)tv[1];
      a2 += w * (float)tv[2];
      a3 += w * (float)tv[3];
    }

    float r0 = fmaxf(a0 + bb.x, 0.f);
    float r1 = fmaxf(a1 + bb.y, 0.f);
    float r2 = fmaxf(a2 + bb.z, 0.f);
    float r3 = fmaxf(a3 + bb.w, 0.f);

    float gx = r0 * v0.x + r1 * v1.x + r2 * v2.x + r3 * v3.x;
    float gy = r0 * v0.y + r1 * v1.y + r2 * v2.y + r3 * v3.y;
    float gz = r0 * v0.z + r1 * v1.z + r2 * v2.z + r3 * v3.z;
    float gw = r0 * v0.w + r1 * v1.w + r2 * v2.w + r3 * v3.w;
#pragma unroll
    for (int d = 32; d > 0; d >>= 1) {
      gx += __shfl_down(gx, d, 64);
      gy += __shfl_down(gy, d, 64);
      gz += __shfl_down(gz, d, 64);
      gw += __shfl_down(gw, d, 64);
    }
    if (lane == 0) G[node] = make_float4(gx, gy, gz, gw);
  }
}

// ---- aggP: quad-per-node, grid-strided ----
__device__ void aggP_body(const float4* __restrict__ G, const unsigned int* __restrict__ pmeta,
                          const int* __restrict__ offsets, float4* __restrict__ P,
                          int N, int E) {
  int nvb = (N + 63) >> 6;
  int j = threadIdx.x & 3;
  for (int vb = blockIdx.x; vb < nvb; vb += gridDim.x) {
    int node = vb * 64 + (threadIdx.x >> 2);
    if (node < N) {
      int beg = offsets[node], end = offsets[node + 1];
      beg = beg < 0 ? 0 : (beg > E ? E : beg);
      end = end < beg ? beg : (end > E ? E : end);
      float ax = 0.f, ay = 0.f, az = 0.f, aw = 0.f;
      int p = beg + j;
      for (; p + 4 < end; p += 8) {
        unsigned int m0 = pmeta[p], m1 = pmeta[p + 4];
        int s0 = (int)(m0 & 0xFFFFu); s0 = s0 >= N ? N - 1 : s0;
        int s1 = (int)(m1 & 0xFFFFu); s1 = s1 >= N ? N - 1 : s1;
        float4 g0 = G[s0], g1 = G[s1];
        float w0 = __uint_as_float(m0 & 0xFFFF0000u);
        float w1 = __uint_as_float(m1 & 0xFFFF0000u);
        ax += w0 * g0.x + w1 * g1.x;
        ay += w0 * g0.y + w1 * g1.y;
        az += w0 * g0.z + w1 * g1.z;
        aw += w0 * g0.w + w1 * g1.w;
      }
      if (p < end) {
        unsigned int mm = pmeta[p];
        int s = (int)(mm & 0xFFFFu); s = s >= N ? N - 1 : s;
        float w = __uint_as_float(mm & 0xFFFF0000u);
        float4 g = G[s];
        ax += w * g.x; ay += w * g.y; az += w * g.z; aw += w * g.w;
      }
      ax += __shfl_xor(ax, 1, 64); ax += __shfl_xor(ax, 2, 64);
      ay += __shfl_xor(ay, 1, 64); ay += __shfl_xor(ay, 2, 64);
      az += __shfl_xor(az, 1, 64); az += __shfl_xor(az, 2, 64);
      aw += __shfl_xor(aw, 1, 64); aw += __shfl_xor(aw, 2, 64);
      if (j == 0) P[node] = make_float4(ax, ay, az, aw);
    }
  }
}

// ---- query: grid-strided ----
__device__ void query_body(const int* __restrict__ qe, const float4* __restrict__ P,
                           const float* __restrict__ cc, float* __restrict__ out,
                           int Q, int N) {
  int nvb = (Q + 255) >> 8;
  for (int vb = blockIdx.x; vb < nvb; vb += gridDim.x) {
    int q = vb * 256 + threadIdx.x;
    if (q < Q) {
      int n0 = qe[2 * q + 0]; n0 = n0 < 0 ? 0 : (n0 >= N ? N - 1 : n0);
      int n1 = qe[2 * q + 1]; n1 = n1 < 0 ? 0 : (n1 >= N ? N - 1 : n1);
      float4 p0 = P[n0];
      float4 p1 = P[n1];
      float l0 = p0.x + p1.z + cc[0];
      float l1 = p0.y + p1.w + cc[1];
      float m = fmaxf(l0, l1);
      float lse = m + logf(expf(l0 - m) + expf(l1 - m));
      out[2 * q + 0] = l0 - lse;
      out[2 * q + 1] = l1 - lse;
    }
  }
}

// =================== cooperative mega-kernels (2 launches total) =================

__global__ __launch_bounds__(256, 2) void megaA(const float* __restrict__ W1,
    const float* __restrict__ W2, bf16* __restrict__ Wt1, const int* __restrict__ dst,
    int* __restrict__ phist, const float* __restrict__ Wl, const float* __restrict__ b2,
    const float* __restrict__ bl, float4* __restrict__ V, float* __restrict__ cc,
    int* __restrict__ bbase, int* __restrict__ pbase, int* __restrict__ offs,
    const float* __restrict__ x, bf16* __restrict__ bufT, const int* __restrict__ src,
    const float* __restrict__ ew, uint2* __restrict__ tmp,
    unsigned int* __restrict__ pmeta, int E, int N, int nbkt) {
  cg::grid_group grid = cg::this_grid();
  __shared__ __align__(16) char sm[SMEM_A];

  // phase 1: k1 (transpose + hists + V/cc)
  for (int vb = blockIdx.x; vb < 513; vb += gridDim.x)
    k1_body(vb, sm, W1, W2, Wt1, dst, phist, Wl, b2, bl, V, cc, E, N);
  grid.sync();
  // phase 2: p2 (single block)
  if (blockIdx.x == 0) p2_body(sm, phist, bbase, pbase, offs, nbkt, N);
  grid.sync();
  // phase 3: gemm1
  gemm_body(x, Wt1, bufT, N, blockIdx.x, gridDim.x, (bf16*)sm);
  grid.sync();
  // phase 4: p3 scatter
  for (int vb = blockIdx.x; vb < 256; vb += gridDim.x)
    p3_body(vb, sm, src, dst, ew, phist, pbase, tmp, E, N);
  grid.sync();
  // phase 5: p4 sort
  for (int vb = blockIdx.x; vb < nbkt; vb += gridDim.x)
    p4_body(vb, sm, tmp, bbase, pmeta, offs, N, E);
}

__global__ __launch_bounds__(256, 8) void megaB(const bf16* __restrict__ bufT,
    const unsigned int* __restrict__ pmeta, const int* __restrict__ offs,
    const float* __restrict__ b1, const float4* __restrict__ V, float4* __restrict__ G,
    float4* __restrict__ P, const int* __restrict__ qe, const float* __restrict__ cc,
    float* __restrict__ out, int N, int E, int Q) {
  cg::grid_group grid = cg::this_grid();
  agg_body(bufT, pmeta, offs, b1, V, G, N, E);
  grid.sync();
  aggP_body(G, pmeta, offs, P, N, E);
  grid.sync();
  query_body(qe, P, cc, out, Q, N);
}

// =================== standalone fallback kernels (round-6 proven path) ===========

__global__ __launch_bounds__(256) void k1_prep(const float* __restrict__ W1,
    const float* __restrict__ W2, bf16* __restrict__ Wt1, const int* __restrict__ dst,
    int* __restrict__ phist, const float* __restrict__ Wl, const float* __restrict__ b2,
    const float* __restrict__ bl, float4* __restrict__ V, float* __restrict__ cc,
    int E, int N) {
  __shared__ __align__(16) char sm[6144];
  k1_body(blockIdx.x, sm, W1, W2, Wt1, dst, phist, Wl, b2, bl, V, cc, E, N);
}

__global__ __launch_bounds__(256) void p2_scan(const int* __restrict__ phist,
    int* __restrict__ bbase, int* __restrict__ pbase, int* __restrict__ offs,
    int nbkt, int Nn) {
  __shared__ __align__(16) char sm[16];
  p2_body(sm, phist, bbase, pbase, offs, nbkt, Nn);
}

__global__ __launch_bounds__(256, 2) void gemm1(const float* __restrict__ A,
    const bf16* __restrict__ Bt, bf16* __restrict__ C, int M) {
  __shared__ __align__(16) char sm[64 * AROW * 2];
  gemm_body(A, Bt, C, M, blockIdx.x, gridDim.x, (bf16*)sm);
}

__global__ __launch_bounds__(256) void p3_scatter(const int* __restrict__ src,
    const int* __restrict__ dst, const float* __restrict__ ew,
    const int* __restrict__ phist, const int* __restrict__ pbase,
    uint2* __restrict__ tmp, int E, int N) {
  __shared__ __align__(16) char sm[35856];
  p3_body(blockIdx.x, sm, src, dst, ew, phist, pbase, tmp, E, N);
}

__global__ __launch_bounds__(256) void p4_sort(const uint2* __restrict__ tmp,
    const int* __restrict__ bbase, unsigned int* __restrict__ pmeta,
    int* __restrict__ offs, int Nn, int E) {
  __shared__ __align__(16) char sm[SMEM_A];
  p4_body(blockIdx.x, sm, tmp, bbase, pmeta, offs, Nn, E);
}

__global__ __launch_bounds__(256) void agg1G(const bf16* __restrict__ T,
    const unsigned int* __restrict__ pmeta, const int* __restrict__ offsets,
    const float* __restrict__ bias, const float4* __restrict__ V,
    float4* __restrict__ G, int N, int E) {
  agg_body(T, pmeta, offsets, bias, V, G, N, E);
}

__global__ __launch_bounds__(256) void aggP(const float4* __restrict__ G,
    const unsigned int* __restrict__ pmeta, const int* __restrict__ offsets,
    float4* __restrict__ P, int N, int E) {
  aggP_body(G, pmeta, offsets, P, N, E);
}

__global__ __launch_bounds__(256) void query_small(const int* __restrict__ qe,
    const float4* __restrict__ P, const float* __restrict__ cc,
    float* __restrict__ out, int Q, int N) {
  query_body(qe, P, cc, out, Q, N);
}

// ---------------- host launcher ----------------

extern "C" void kernel_launch(void* const* d_in, const int* in_sizes, int n_in,
                              void* d_out, int out_size, void* d_ws, size_t ws_size,
                              hipStream_t stream) {
  const float* x  = (const float*)d_in[0];
  const int*   ei = (const int*)d_in[1];
  const int*   qe = (const int*)d_in[2];
  const float* ew = (const float*)d_in[3];
  const float* W1 = (const float*)d_in[4];
  const float* b1 = (const float*)d_in[5];
  const float* W2 = (const float*)d_in[6];
  const float* b2 = (const float*)d_in[7];
  const float* Wl = (const float*)d_in[8];
  const float* bl = (const float*)d_in[9];

  int N = in_sizes[0] / FDIM;  // 50000
  int E = in_sizes[1] / 2;     // 1,000,000
  int Q = in_sizes[2] / 2;     // 100,000
  const int* srcv = ei;
  const int* dstv = ei + E;
  int nbkt = (N + 255) >> 8;   // 196
  int ntiles = (N + 63) >> 6;  // 782
  float* outp = (float*)d_out;

  size_t off = 0;
  auto alloc = [&](size_t bytes) -> void* {
    void* p = (char*)d_ws + off;
    off += (bytes + 255) & ~(size_t)255;
    return p;
  };
  bf16* bufT  = (bf16*)alloc((size_t)N * FDIM * 2);   // t1 = x@W1 (row-major)
  uint2* tmp  = (uint2*)alloc((size_t)E * 8);         // bucket-scattered {meta,dst}
  bf16* Wt1   = (bf16*)alloc((size_t)FDIM * FDIM * 2);
  int* offs   = (int*)alloc((size_t)(N + 1) * 4);
  unsigned int* pmeta = (unsigned int*)alloc((size_t)E * 4);
  float4* G   = (float4*)alloc((size_t)N * 16);
  float4* P   = (float4*)alloc((size_t)N * 16);
  float4* V   = (float4*)alloc(256 * 16);
  float* cc   = (float*)alloc(2 * 4);
  int* phist  = (int*)alloc(256 * 256 * 4);
  int* pbase  = (int*)alloc(256 * 256 * 4);
  int* bbase  = (int*)alloc(257 * 4);

  if (off > ws_size) {
    flag_kernel<<<(out_size + 255) / 256, 256, 0, stream>>>((float*)d_out, out_size);
    return;
  }

  int dev = 0;
  hipGetDevice(&dev);
  int coop = 0;
  hipDeviceGetAttribute(&coop, hipDeviceAttributeCooperativeLaunch, dev);

  bool done = false;
  if (coop) {
    void* argsA[] = {(void*)&W1, (void*)&W2, (void*)&Wt1, (void*)&dstv, (void*)&phist,
                     (void*)&Wl, (void*)&b2, (void*)&bl, (void*)&V, (void*)&cc,
                     (void*)&bbase, (void*)&pbase, (void*)&offs, (void*)&x, (void*)&bufT,
                     (void*)&srcv, (void*)&ew, (void*)&tmp, (void*)&pmeta,
                     (void*)&E, (void*)&N, (void*)&nbkt};
    void* argsB[] = {(void*)&bufT, (void*)&pmeta, (void*)&offs, (void*)&b1, (void*)&V,
                     (void*)&G, (void*)&P, (void*)&qe, (void*)&cc, (void*)&outp,
                     (void*)&N, (void*)&E, (void*)&Q};
    hipError_t eA = hipLaunchCooperativeKernel((const void*)megaA, dim3(512), dim3(256),
                                               argsA, 0, stream);
    if (eA == hipSuccess) {
      hipError_t eB = hipLaunchCooperativeKernel((const void*)megaB, dim3(2048), dim3(256),
                                                 argsB, 0, stream);
      done = (eB == hipSuccess);
    }
  }

  if (!done) {
    // fallback: proven 8-launch pipeline (round-6 structure)
    k1_prep<<<513, 256, 0, stream>>>(W1, W2, Wt1, dstv, phist, Wl, b2, bl, V, cc, E, N);
    p2_scan<<<1, 256, 0, stream>>>(phist, bbase, pbase, offs, nbkt, N);
    gemm1<<<ntiles, 256, 0, stream>>>(x, Wt1, bufT, N);
    p3_scatter<<<256, 256, 0, stream>>>(srcv, dstv, ew, phist, pbase, tmp, E, N);
    p4_sort<<<nbkt, 256, 0, stream>>>(tmp, bbase, pmeta, offs, N, E);
    agg1G<<<2048, 256, 0, stream>>>(bufT, pmeta, offs, b1, V, G, N, E);
    aggP<<<(N * 4 + 255) / 256, 256, 0, stream>>>(G, pmeta, offs, P, N, E);
    query_small<<<(Q + 255) / 256, 256, 0, stream>>>(qe, P, cc, outp, Q, N);
  }
}

// Round 11
// 249.502 us; speedup vs baseline: 4.0725x; 4.0725x over previous
//
#include <hip/hip_runtime.h>
#include <hip/hip_bf16.h>
#include <math.h>

typedef __bf16 bf16;
typedef __bf16 v8bf __attribute__((ext_vector_type(8)));
typedef __bf16 v4bf __attribute__((ext_vector_type(4)));
typedef float  v4f  __attribute__((ext_vector_type(4)));

#define FDIM 256
#define BKT_CAP 8192
#define AROW 264        // LDS A row stride (528B -> 2-way bank aliasing, free)
#define GEMM_BLOCKS 352 // + 160 p3 blocks = 512 total -> all co-resident at 2 blk/CU
#define K3_BLOCKS 512
#define P3_BLOCKS (K3_BLOCKS - GEMM_BLOCKS)

// ---------------- utility ----------------

__global__ __launch_bounds__(256) void flag_kernel(float* __restrict__ out, int n) {
  int i = blockIdx.x * 256 + threadIdx.x;
  if (i < n) out[i] = 1.0e9f;
}

// ---------------- K1: Wt1 transpose + per-block bucket hists + V projection -------
// blocks 0..255: Wt1 transpose (Wt2 dropped — collapsed math never reads it);
// 256..511: per-block hist -> phist; block 512: V = W2 @ [Wl_top | Wl_bot] + cc[2].
__global__ __launch_bounds__(256) void k1_prep(const float* __restrict__ W1,
                                               const float* __restrict__ W2,
                                               bf16* __restrict__ Wt1,
                                               const int* __restrict__ dst,
                                               int* __restrict__ phist,
                                               const float* __restrict__ Wl,
                                               const float* __restrict__ b2,
                                               const float* __restrict__ bl,
                                               float4* __restrict__ V,
                                               float* __restrict__ cc,
                                               int E, int N, int nbkt) {
  __shared__ int h[256];
  __shared__ float sWl[1024];   // Wl[512][2]
  __shared__ float red[256];
  int b = blockIdx.x;
  int t = threadIdx.x;
  if (b < 256) {
    int k = b;
    Wt1[t * FDIM + k] = (bf16)W1[k * FDIM + t];
  } else if (b < 512) {
    int pb = b - 256;  // 0..255
    h[t] = 0;
    __syncthreads();
    for (int e = pb * 256 + t; e < E; e += 256 * 256) {
      int d = dst[e];
      d = d < 0 ? 0 : (d >= N ? N - 1 : d);
      atomicAdd(&h[d >> 8], 1);
    }
    __syncthreads();
    phist[pb * 256 + t] = h[t];   // write ALL slots (p2 sums them; no memset)
  } else {
    // V[k] = (W2[k]·Wl_top0, W2[k]·Wl_top1, W2[k]·Wl_bot0, W2[k]·Wl_bot1)
#pragma unroll
    for (int j = 0; j < 4; ++j) sWl[j * 256 + t] = Wl[j * 256 + t];
    __syncthreads();
    const float* w2row = W2 + (size_t)t * FDIM;
    float4 acc = make_float4(0.f, 0.f, 0.f, 0.f);
    for (int j = 0; j < 256; ++j) {
      float w = w2row[j];
      acc.x += w * sWl[2 * j + 0];
      acc.y += w * sWl[2 * j + 1];
      acc.z += w * sWl[512 + 2 * j + 0];
      acc.w += w * sWl[512 + 2 * j + 1];
    }
    V[t] = acc;
    // cc[c] = sum_j b2[j]*(Wl[j][c] + Wl[256+j][c]) + bl[c]
    float bj = b2[t];
    red[t] = bj * (sWl[2 * t + 0] + sWl[512 + 2 * t + 0]);
    __syncthreads();
    if (t == 0) {
      float s = 0.f;
      for (int j = 0; j < 256; ++j) s += red[j];
      cc[0] = s + bl[0];
    }
    __syncthreads();
    red[t] = bj * (sWl[2 * t + 1] + sWl[512 + 2 * t + 1]);
    __syncthreads();
    if (t == 0) {
      float s = 0.f;
      for (int j = 0; j < 256; ++j) s += red[j];
      cc[1] = s + bl[1];
    }
  }
}

// ---------------- p2: sum per-block hists, scan -> bbase/gcur; offs[N]=E ------
__global__ __launch_bounds__(256) void p2_scan(const int* __restrict__ phist,
                                               int* __restrict__ bbase,
                                               int* __restrict__ gcur,
                                               int* __restrict__ offs,
                                               int nbkt, int Nn) {
  __shared__ int wsum[4];
  int t = threadIdx.x, lane = t & 63, wv = t >> 6;
  int v = 0;
  for (int pb = 0; pb < 256; ++pb) v += phist[pb * 256 + t];  // coalesced across t
  if (t >= nbkt) v = 0;
  int x = v;
#pragma unroll
  for (int d = 1; d < 64; d <<= 1) {
    int y = __shfl_up(x, d, 64);
    if (lane >= d) x += y;
  }
  if (lane == 63) wsum[wv] = x;
  __syncthreads();
  int woff = 0;
  if (wv >= 1) woff += wsum[0];
  if (wv >= 2) woff += wsum[1];
  if (wv >= 3) woff += wsum[2];
  int incl = woff + x;
  int excl = incl - v;
  if (t < nbkt) { bbase[t] = excl; gcur[t] = excl; }
  if (t == 255) {
    bbase[nbkt] = incl;
    offs[Nn] = incl;
  }
}

// ---------------- GEMM v4 body ----------------

__device__ inline void stage64(const float* __restrict__ A, bf16* __restrict__ As,
                               int row0, int M, int tid) {
#pragma unroll
  for (int j = 0; j < 8; ++j) {
    int g = j * 2048 + tid * 8;
    int r = g >> 8, c = g & 255;
    int gr = row0 + r; if (gr >= M) gr = M - 1;
    const float* p = A + (size_t)gr * FDIM + c;
    float4 f0 = *reinterpret_cast<const float4*>(p);
    float4 f1 = *reinterpret_cast<const float4*>(p + 4);
    v8bf o;
    o[0] = (bf16)f0.x; o[1] = (bf16)f0.y; o[2] = (bf16)f0.z; o[3] = (bf16)f0.w;
    o[4] = (bf16)f1.x; o[5] = (bf16)f1.y; o[6] = (bf16)f1.z; o[7] = (bf16)f1.w;
    *reinterpret_cast<v8bf*>(As + r * AROW + c) = o;
  }
}

__device__ inline void gemm_body(const float* __restrict__ A, const bf16* __restrict__ Bt,
                                 bf16* __restrict__ C, int M, int bid, int nblocks,
                                 bf16* __restrict__ As) {
  const int K = FDIM, N = FDIM;
  int tid = threadIdx.x;
  int wave = tid >> 6;
  int lane = tid & 63;
  int l15 = lane & 15, quad = lane >> 4;

  v8bf bfr[4][8];
#pragma unroll
  for (int nn = 0; nn < 4; ++nn) {
    const bf16* bp = Bt + (size_t)(wave * 64 + nn * 16 + l15) * K + quad * 8;
#pragma unroll
    for (int kk = 0; kk < 8; ++kk)
      bfr[nn][kk] = *reinterpret_cast<const v8bf*>(bp + kk * 32);
  }

  int ntiles = (M + 63) >> 6;
  for (int tile = bid; tile < ntiles; tile += nblocks) {
    int row0 = tile * 64;
    __syncthreads();
    stage64(A, As, row0, M, tid);
    __syncthreads();

#pragma unroll
    for (int st = 0; st < 4; ++st) {
      v8bf afr[8];
#pragma unroll
      for (int kk = 0; kk < 8; ++kk)
        afr[kk] = *reinterpret_cast<const v8bf*>(As + (st * 16 + l15) * AROW + quad * 8 + kk * 32);

      v4f acc[4];
#pragma unroll
      for (int nn = 0; nn < 4; ++nn) acc[nn] = (v4f){0.f, 0.f, 0.f, 0.f};

#pragma unroll
      for (int kk = 0; kk < 8; ++kk)
#pragma unroll
        for (int nn = 0; nn < 4; ++nn)
          acc[nn] = __builtin_amdgcn_mfma_f32_16x16x32_bf16(afr[kk], bfr[nn][kk], acc[nn], 0, 0, 0);

#pragma unroll
      for (int nn = 0; nn < 4; ++nn)
#pragma unroll
        for (int r = 0; r < 4; ++r) {
          int row = row0 + st * 16 + quad * 4 + r;
          int col = wave * 64 + nn * 16 + l15;
          if (row < M) C[(size_t)row * N + col] = (bf16)acc[nn][r];
        }
    }
  }
}

// ---------------- p3 body: LDS-binned scatter into bucket regions ----------------
__device__ inline void p3_body(const int* __restrict__ src, const int* __restrict__ dst,
                               const float* __restrict__ ew, int* __restrict__ gcur,
                               uint2* __restrict__ tmp, int E, int N, int nbkt,
                               int pb, int nblocks, int* h, int* base, int* cnt) {
  int t = threadIdx.x;
  int chunk = (E + nblocks - 1) / nblocks;
  int lo = pb * chunk;
  int hi = lo + chunk; if (hi > E) hi = E;
  h[t] = 0; cnt[t] = 0;
  __syncthreads();
  for (int e = lo + t; e < hi; e += 256) {
    int d = dst[e];
    d = d < 0 ? 0 : (d >= N ? N - 1 : d);
    atomicAdd(&h[d >> 8], 1);
  }
  __syncthreads();
  if (t < nbkt) base[t] = atomicAdd(&gcur[t], h[t]);
  __syncthreads();
  for (int e = lo + t; e < hi; e += 256) {
    int d = dst[e];
    d = d < 0 ? 0 : (d >= N ? N - 1 : d);
    int b = d >> 8;
    int sv = src[e];
    sv = sv < 0 ? 0 : (sv >= N ? N - 1 : sv);
    unsigned int u = __float_as_uint(ew[e]);
    unsigned int wbits = ((u + 0x7FFFu + ((u >> 16) & 1u)) & 0xFFFF0000u);  // RN bf16
    unsigned int meta = wbits | (unsigned int)(sv & 0xFFFF);
    int r = atomicAdd(&cnt[b], 1);
    int pos = base[b] + r;
    if (pos >= 0 && pos < E) tmp[pos] = make_uint2(meta, (unsigned int)d);
  }
}

// ---------------- K3: gemm1 (0..GEMM_BLOCKS-1) + p3 (rest) — all co-resident ----
__global__ __launch_bounds__(256, 2) void k3_gemm1_p3(const float* __restrict__ x,
                                                      const bf16* __restrict__ Wt1,
                                                      bf16* __restrict__ bufT, int M,
                                                      const int* __restrict__ src,
                                                      const int* __restrict__ dst,
                                                      const float* __restrict__ ew,
                                                      int* __restrict__ gcur,
                                                      uint2* __restrict__ tmp,
                                                      int E, int N, int nbkt) {
  __shared__ bf16 As[64 * AROW];
  __shared__ int h[256], base[256], cnt[256];
  if (blockIdx.x < GEMM_BLOCKS)
    gemm_body(x, Wt1, bufT, M, blockIdx.x, GEMM_BLOCKS, As);
  else
    p3_body(src, dst, ew, gcur, tmp, E, N, nbkt, blockIdx.x - GEMM_BLOCKS, P3_BLOCKS,
            h, base, cnt);
}

// ---------------- p4: per-bucket LDS count-sort -> pmeta + node offsets --------
__global__ __launch_bounds__(256) void p4_sort(const uint2* __restrict__ tmp,
                                               const int* __restrict__ bbase,
                                               unsigned int* __restrict__ pmeta,
                                               int* __restrict__ offs,
                                               int Nn, int E) {
  __shared__ uint2 ent[BKT_CAP];
  __shared__ int h2[256], ex2[256], c2[256];
  __shared__ int wsum[4];
  int b = blockIdx.x, t = threadIdx.x, lane = t & 63, wv = t >> 6;
  int s0 = bbase[b], s1 = bbase[b + 1];
  int count = s1 - s0;
  if (count < 0) count = 0;
  if (count > BKT_CAP) count = BKT_CAP;
  for (int i = t; i < count; i += 256) ent[i] = tmp[s0 + i];
  h2[t] = 0; c2[t] = 0;
  __syncthreads();
  for (int i = t; i < count; i += 256) atomicAdd(&h2[ent[i].y & 255u], 1);
  __syncthreads();
  int v = h2[t];
  int x = v;
#pragma unroll
  for (int d = 1; d < 64; d <<= 1) {
    int y = __shfl_up(x, d, 64);
    if (lane >= d) x += y;
  }
  if (lane == 63) wsum[wv] = x;
  __syncthreads();
  int woff = 0;
  if (wv >= 1) woff += wsum[0];
  if (wv >= 2) woff += wsum[1];
  if (wv >= 3) woff += wsum[2];
  int excl = woff + x - v;
  ex2[t] = excl;
  int node = (b << 8) + t;
  if (node < Nn) offs[node] = s0 + excl;
  __syncthreads();
  for (int i = t; i < count; i += 256) {
    int l = (int)(ent[i].y & 255u);
    int r = atomicAdd(&c2[l], 1);
    int pos = s0 + ex2[l] + r;
    if (pos >= 0 && pos < E) pmeta[pos] = ent[i].x;
  }
}

// ---------------- agg1G (round-2 proven): grid-stride + scalarized meta ----
__global__ __launch_bounds__(256) void agg1G(const bf16* __restrict__ T,
                                             const unsigned int* __restrict__ pmeta,
                                             const int* __restrict__ offsets,
                                             const float* __restrict__ bias,
                                             const float4* __restrict__ V,
                                             float4* __restrict__ G, int N, int E) {
  int wid = blockIdx.x * 4 + (threadIdx.x >> 6);
  int nw = gridDim.x * 4;
  int lane = threadIdx.x & 63;
  int f = lane * 4;
  const bf16* Tf = T + f;

  float4 bb = *reinterpret_cast<const float4*>(bias + f);
  float4 v0 = V[f + 0], v1 = V[f + 1], v2 = V[f + 2], v3 = V[f + 3];

  for (int node = wid; node < N; node += nw) {
    int nb = __builtin_amdgcn_readfirstlane(node);
    int beg = offsets[nb], end = offsets[nb + 1];
    beg = beg < 0 ? 0 : (beg > E ? E : beg);
    end = end < beg ? beg : (end > E ? E : end);
    int cnt = end - beg;
    const unsigned int* m = pmeta + beg;

    float a0 = 0.f, a1 = 0.f, a2 = 0.f, a3 = 0.f;
    int p = 0;
    for (; p + 8 <= cnt; p += 8) {
      unsigned int mv0 = m[p + 0], mv1 = m[p + 1], mv2 = m[p + 2], mv3 = m[p + 3];
      unsigned int mv4 = m[p + 4], mv5 = m[p + 5], mv6 = m[p + 6], mv7 = m[p + 7];
      v4bf t0 = *reinterpret_cast<const v4bf*>(Tf + ((size_t)(mv0 & 0xFFFFu) << 8));
      v4bf t1 = *reinterpret_cast<const v4bf*>(Tf + ((size_t)(mv1 & 0xFFFFu) << 8));
      v4bf t2 = *reinterpret_cast<const v4bf*>(Tf + ((size_t)(mv2 & 0xFFFFu) << 8));
      v4bf t3 = *reinterpret_cast<const v4bf*>(Tf + ((size_t)(mv3 & 0xFFFFu) << 8));
      v4bf t4 = *reinterpret_cast<const v4bf*>(Tf + ((size_t)(mv4 & 0xFFFFu) << 8));
      v4bf t5 = *reinterpret_cast<const v4bf*>(Tf + ((size_t)(mv5 & 0xFFFFu) << 8));
      v4bf t6 = *reinterpret_cast<const v4bf*>(Tf + ((size_t)(mv6 & 0xFFFFu) << 8));
      v4bf t7 = *reinterpret_cast<const v4bf*>(Tf + ((size_t)(mv7 & 0xFFFFu) << 8));
      float w0 = __uint_as_float(mv0 & 0xFFFF0000u);
      float w1 = __uint_as_float(mv1 & 0xFFFF0000u);
      float w2 = __uint_as_float(mv2 & 0xFFFF0000u);
      float w3 = __uint_as_float(mv3 & 0xFFFF0000u);
      float w4 = __uint_as_float(mv4 & 0xFFFF0000u);
      float w5 = __uint_as_float(mv5 & 0xFFFF0000u);
      float w6 = __uint_as_float(mv6 & 0xFFFF0000u);
      float w7 = __uint_as_float(mv7 & 0xFFFF0000u);
      a0 += w0 * (float)t0[0]; a1 += w0 * (float)t0[1]; a2 += w0 * (float)t0[2]; a3 += w0 * (float)t0[3];
      a0 += w1 * (float)t1[0]; a1 += w1 * (float)t1[1]; a2 += w1 * (float)t1[2]; a3 += w1 * (float)t1[3];
      a0 += w2 * (float)t2[0]; a1 += w2 * (float)t2[1]; a2 += w2 * (float)t2[2]; a3 += w2 * (float)t2[3];
      a0 += w3 * (float)t3[0]; a1 += w3 * (float)t3[1]; a2 += w3 * (float)t3[2]; a3 += w3 * (float)t3[3];
      a0 += w4 * (float)t4[0]; a1 += w4 * (float)t4[1]; a2 += w4 * (float)t4[2]; a3 += w4 * (float)t4[3];
      a0 += w5 * (float)t5[0]; a1 += w5 * (float)t5[1]; a2 += w5 * (float)t5[2]; a3 += w5 * (float)t5[3];
      a0 += w6 * (float)t6[0]; a1 += w6 * (float)t6[1]; a2 += w6 * (float)t6[2]; a3 += w6 * (float)t6[3];
      a0 += w7 * (float)t7[0]; a1 += w7 * (float)t7[1]; a2 += w7 * (float)t7[2]; a3 += w7 * (float)t7[3];
    }
    for (; p < cnt; ++p) {
      unsigned int mv = m[p];
      float w = __uint_as_float(mv & 0xFFFF0000u);
      v4bf tv = *reinterpret_cast<const v4bf*>(Tf + ((size_t)(mv & 0xFFFFu) << 8));
      a0 += w * (float)tv[0];
      a1 += w * (float)tv[1];
      a2 += w * (float)tv[2];
      a3 += w * (float)tv[3];
    }

    float r0 = fmaxf(a0 + bb.x, 0.f);
    float r1 = fmaxf(a1 + bb.y, 0.f);
    float r2 = fmaxf(a2 + bb.z, 0.f);
    float r3 = fmaxf(a3 + bb.w, 0.f);

    float gx = r0 * v0.x + r1 * v1.x + r2 * v2.x + r3 * v3.x;
    float gy = r0 * v0.y + r1 * v1.y + r2 * v2.y + r3 * v3.y;
    float gz = r0 * v0.z + r1 * v1.z + r2 * v2.z + r3 * v3.z;
    float gw = r0 * v0.w + r1 * v1.w + r2 * v2.w + r3 * v3.w;
#pragma unroll
    for (int d = 32; d > 0; d >>= 1) {
      gx += __shfl_down(gx, d, 64);
      gy += __shfl_down(gy, d, 64);
      gz += __shfl_down(gz, d, 64);
      gw += __shfl_down(gw, d, 64);
    }
    if (lane == 0) G[node] = make_float4(gx, gy, gz, gw);
  }
}

// ---------------- aggP: P[n] = sum_e w_e * G[src_e]  (16B/edge, L2-resident table) ----
__global__ __launch_bounds__(256) void aggP(const float4* __restrict__ G,
                                            const unsigned int* __restrict__ pmeta,
                                            const int* __restrict__ offsets,
                                            float4* __restrict__ P, int N, int E) {
  int node = blockIdx.x * 256 + threadIdx.x;
  if (node >= N) return;
  int beg = offsets[node], end = offsets[node + 1];
  beg = beg < 0 ? 0 : (beg > E ? E : beg);
  end = end < beg ? beg : (end > E ? E : end);
  float ax = 0.f, ay = 0.f, az = 0.f, aw = 0.f;
  int p = beg;
  for (; p + 4 <= end; p += 4) {
    unsigned int m0 = pmeta[p + 0], m1 = pmeta[p + 1], m2 = pmeta[p + 2], m3 = pmeta[p + 3];
    int s0 = (int)(m0 & 0xFFFFu); s0 = s0 >= N ? N - 1 : s0;
    int s1 = (int)(m1 & 0xFFFFu); s1 = s1 >= N ? N - 1 : s1;
    int s2 = (int)(m2 & 0xFFFFu); s2 = s2 >= N ? N - 1 : s2;
    int s3 = (int)(m3 & 0xFFFFu); s3 = s3 >= N ? N - 1 : s3;
    float4 g0 = G[s0], g1 = G[s1], g2 = G[s2], g3 = G[s3];
    float w0 = __uint_as_float(m0 & 0xFFFF0000u);
    float w1 = __uint_as_float(m1 & 0xFFFF0000u);
    float w2 = __uint_as_float(m2 & 0xFFFF0000u);
    float w3 = __uint_as_float(m3 & 0xFFFF0000u);
    ax += w0 * g0.x + w1 * g1.x + w2 * g2.x + w3 * g3.x;
    ay += w0 * g0.y + w1 * g1.y + w2 * g2.y + w3 * g3.y;
    az += w0 * g0.z + w1 * g1.z + w2 * g2.z + w3 * g3.z;
    aw += w0 * g0.w + w1 * g1.w + w2 * g2.w + w3 * g3.w;
  }
  for (; p < end; ++p) {
    unsigned int mm = pmeta[p];
    int s = (int)(mm & 0xFFFFu); s = s >= N ? N - 1 : s;
    float w = __uint_as_float(mm & 0xFFFF0000u);
    float4 g = G[s];
    ax += w * g.x; ay += w * g.y; az += w * g.z; aw += w * g.w;
  }
  P[node] = make_float4(ax, ay, az, aw);
}

// ---------------- query: logits from P + cc, log-softmax ----------------
__global__ __launch_bounds__(256) void query_small(const int* __restrict__ qe,
                                                   const float4* __restrict__ P,
                                                   const float* __restrict__ cc,
                                                   float* __restrict__ out, int Q, int N) {
  int q = blockIdx.x * 256 + threadIdx.x;
  if (q >= Q) return;
  int n0 = qe[2 * q + 0]; n0 = n0 < 0 ? 0 : (n0 >= N ? N - 1 : n0);
  int n1 = qe[2 * q + 1]; n1 = n1 < 0 ? 0 : (n1 >= N ? N - 1 : n1);
  float4 p0 = P[n0];
  float4 p1 = P[n1];
  float l0 = p0.x + p1.z + cc[0];
  float l1 = p0.y + p1.w + cc[1];
  float m = fmaxf(l0, l1);
  float lse = m + logf(expf(l0 - m) + expf(l1 - m));
  out[2 * q + 0] = l0 - lse;
  out[2 * q + 1] = l1 - lse;
}

// ---------------- host launcher ----------------

extern "C" void kernel_launch(void* const* d_in, const int* in_sizes, int n_in,
                              void* d_out, int out_size, void* d_ws, size_t ws_size,
                              hipStream_t stream) {
  const float* x  = (const float*)d_in[0];
  const int*   ei = (const int*)d_in[1];
  const int*   qe = (const int*)d_in[2];
  const float* ew = (const float*)d_in[3];
  const float* W1 = (const float*)d_in[4];
  const float* b1 = (const float*)d_in[5];
  const float* W2 = (const float*)d_in[6];
  const float* b2 = (const float*)d_in[7];
  const float* Wl = (const float*)d_in[8];
  const float* bl = (const float*)d_in[9];

  int N = in_sizes[0] / FDIM;  // 50000
  int E = in_sizes[1] / 2;     // 1,000,000
  int Q = in_sizes[2] / 2;     // 100,000
  const int* srcv = ei;
  const int* dstv = ei + E;
  int nbkt = (N + 255) >> 8;   // 196

  size_t off = 0;
  auto alloc = [&](size_t bytes) -> void* {
    void* p = (char*)d_ws + off;
    off += (bytes + 255) & ~(size_t)255;
    return p;
  };
  bf16* bufT  = (bf16*)alloc((size_t)N * FDIM * 2);   // t1 = x@W1 (row-major)
  uint2* tmp  = (uint2*)alloc((size_t)E * 8);         // bucket-scattered {meta,dst}
  bf16* Wt1   = (bf16*)alloc((size_t)FDIM * FDIM * 2);
  int* offs   = (int*)alloc((size_t)(N + 1) * 4);
  unsigned int* pmeta = (unsigned int*)alloc((size_t)E * 4);
  float4* G   = (float4*)alloc((size_t)N * 16);
  float4* P   = (float4*)alloc((size_t)N * 16);
  float4* V   = (float4*)alloc(256 * 16);
  float* cc   = (float*)alloc(2 * 4);
  int* phist  = (int*)alloc(256 * 256 * 4);
  int* bbase  = (int*)alloc(257 * 4);
  int* gcur   = (int*)alloc(256 * 4);

  if (off > ws_size) {
    flag_kernel<<<(out_size + 255) / 256, 256, 0, stream>>>((float*)d_out, out_size);
    return;
  }

  // K1: Wt1 transpose + per-block hists + V/cc
  k1_prep<<<513, 256, 0, stream>>>(W1, W2, Wt1, dstv, phist, Wl, b2, bl, V, cc,
                                   E, N, nbkt);
  p2_scan<<<1, 256, 0, stream>>>(phist, bbase, gcur, offs, nbkt, N);
  // K3: gemm1 (t1 = x@W1) truly overlapped with p3 edge scatter (512 blocks, all resident)
  k3_gemm1_p3<<<K3_BLOCKS, 256, 0, stream>>>(x, Wt1, bufT, N,
                                             srcv, dstv, ew, gcur, tmp, E, N, nbkt);
  p4_sort<<<nbkt, 256, 0, stream>>>(tmp, bbase, pmeta, offs, N, E);

  // layer 1 + in-register layer-2 collapse: G[n] = relu(agg(t1)+b1) @ V
  agg1G<<<2048, 256, 0, stream>>>(bufT, pmeta, offs, b1, V, G, N, E);

  // layer 2 aggregation in 4-dim space: P[n] = sum_e w_e G[src_e]
  aggP<<<(N + 255) / 256, 256, 0, stream>>>(G, pmeta, offs, P, N, E);

  // per-query combine + log-softmax (cc folds b2/bl constants)
  query_small<<<(Q + 255) / 256, 256, 0, stream>>>(qe, P, cc, (float*)d_out, Q, N);
}